// Round 5
// baseline (74.644 us; speedup 1.0000x reference)
//
#include <hip/hip_runtime.h>
#include <math.h>

// Problem constants (DigitCapsules)
#define B_   64
#define IC   32
#define D_   288   // ICH*WID*HEI = 8*6*6
#define OC   10
#define OCH  16
#define J_   160   // OC*OCH
#define BJ   10240 // B_*J_

// ws layout (floats):
//   US   [0,      327680) : [ic=32][b*160+j]
//   UDp  [327680, 332800) : [block=512][o=10] partial u_dot
//   nacc [332800, 332803) : n accumulator per routing iteration  (own 128B line)
//   bar  [332832]         : (int) arrival counter                (own 128B line,
//                           separated so polls don't contend with nacc RMWs)
//
// Structure: TWO dispatches (in-kernel agent-scope grid barriers measured
// ~10us each vs ~4-5us per kernel boundary; single-dispatch fusion lost).
//
// K1: u_sum, zero duplicated W traffic + 2-deep register software pipeline.
// thread = (dq in 8, j4 in 40); each thread owns ALL 4 b_sub (16 acc) over a
// disjoint 36-d slice -> block issues exactly its 184 KB unique W slice.
// Load batches of 4 d-rows are triple-buffered (A/B/C, fully unrolled ->
// static reg indexing): stage k issues batch k+2 while FMA-ing batch k, so
// ~2 batches of global latency stay hidden per wave on top of 2.5 waves/SIMD
// TLP. FMA order per accumulator unchanged -> bit-identical to round 4.
__global__ __launch_bounds__(320) void k_usum(const float* __restrict__ u,
                                              const float* __restrict__ Wt,
                                              float* __restrict__ US,
                                              float* __restrict__ UDp,
                                              float* __restrict__ nacc,
                                              int* __restrict__ bar) {
    const int ic  = blockIdx.x & 31;
    const int bt  = blockIdx.x >> 5;    // 0..15
    const int tid = threadIdx.x;
    __shared__ float  u_t[D_ * 4];      // [d][b_sub] transposed
    __shared__ float4 part[8][4][40];   // [dq][b_sub][j4]
    __shared__ float  ud_part[OC];
    if (tid < OC) ud_part[tid] = 0.f;
    if (blockIdx.x == 0 && tid == 0) {
        nacc[0] = 0.f; nacc[1] = 0.f; nacc[2] = 0.f;
        *bar = 0;
    }
    // stage u transposed: 288 float4 coalesced loads, scatter to [d][b_sub]
    if (tid < 288) {
        const int b_sub = tid / 72;
        const int f4    = tid - b_sub * 72;
        const int b     = bt * 4 + b_sub;
        float4 v = ((const float4*)(u + (size_t)(b * IC + ic) * D_))[f4];
        u_t[(f4 * 4 + 0) * 4 + b_sub] = v.x;
        u_t[(f4 * 4 + 1) * 4 + b_sub] = v.y;
        u_t[(f4 * 4 + 2) * 4 + b_sub] = v.z;
        u_t[(f4 * 4 + 3) * 4 + b_sub] = v.w;
    }
    __syncthreads();
    {
        const int j4 = tid % 40;
        const int dq = tid / 40;        // 0..7, disjoint 36-d slices
        const float4* wp = (const float4*)(Wt + (size_t)ic * D_ * J_)
                           + (size_t)(dq * 36) * 40 + j4;
        const float4* ut = ((const float4*)u_t) + dq * 36;
        float4 a0 = make_float4(0.f, 0.f, 0.f, 0.f);
        float4 a1 = a0, a2 = a0, a3 = a0;   // acc[b_sub], comps = j
#define ACC16(qv, wv)                                                        \
        a0.x += qv.x * wv.x; a0.y += qv.x * wv.y;                            \
        a0.z += qv.x * wv.z; a0.w += qv.x * wv.w;                            \
        a1.x += qv.y * wv.x; a1.y += qv.y * wv.y;                            \
        a1.z += qv.y * wv.z; a1.w += qv.y * wv.w;                            \
        a2.x += qv.z * wv.x; a2.y += qv.z * wv.y;                            \
        a2.z += qv.z * wv.z; a2.w += qv.z * wv.w;                            \
        a3.x += qv.w * wv.x; a3.y += qv.w * wv.y;                            \
        a3.z += qv.w * wv.z; a3.w += qv.w * wv.w;
#define LOADW(W0, W1, W2, W3, K)                                             \
        W0 = wp[(K + 0) * 40]; W1 = wp[(K + 1) * 40];                        \
        W2 = wp[(K + 2) * 40]; W3 = wp[(K + 3) * 40];
#define CONS(W0, W1, W2, W3, K)                                              \
        { float4 q0 = ut[K + 0], q1 = ut[K + 1],                             \
                 q2 = ut[K + 2], q3 = ut[K + 3];                             \
          ACC16(q0, W0) ACC16(q1, W1) ACC16(q2, W2) ACC16(q3, W3) }
        float4 A0, A1, A2, A3, B0, B1, B2, B3, C0, C1, C2, C3;
        LOADW(A0, A1, A2, A3, 0)
        LOADW(B0, B1, B2, B3, 4)
        LOADW(C0, C1, C2, C3, 8)   CONS(A0, A1, A2, A3, 0)
        LOADW(A0, A1, A2, A3, 12)  CONS(B0, B1, B2, B3, 4)
        LOADW(B0, B1, B2, B3, 16)  CONS(C0, C1, C2, C3, 8)
        LOADW(C0, C1, C2, C3, 20)  CONS(A0, A1, A2, A3, 12)
        LOADW(A0, A1, A2, A3, 24)  CONS(B0, B1, B2, B3, 16)
        LOADW(B0, B1, B2, B3, 28)  CONS(C0, C1, C2, C3, 20)
        LOADW(C0, C1, C2, C3, 32)  CONS(A0, A1, A2, A3, 24)
                                   CONS(B0, B1, B2, B3, 28)
                                   CONS(C0, C1, C2, C3, 32)
#undef CONS
#undef LOADW
#undef ACC16
        part[dq][0][j4] = a0;
        part[dq][1][j4] = a1;
        part[dq][2][j4] = a2;
        part[dq][3][j4] = a3;
    }
    __syncthreads();
    // reduce over dq (ascending -> deterministic), then epilogue
    if (tid < 160) {
        const int jj = tid % 40;
        const int bs = tid / 40;
        float4 r = part[0][bs][jj];
        #pragma unroll
        for (int dq = 1; dq < 8; ++dq) {
            float4 p = part[dq][bs][jj];
            r.x += p.x; r.y += p.y; r.z += p.z; r.w += p.w;
        }
        ((float4*)(US + (size_t)ic * BJ + (bt * 4 + bs) * J_))[jj] = r;
        // u_dot partial: 4 consecutive lanes share o = jj>>2
        float g = r.x + r.y + r.z + r.w;
        g += __shfl_xor(g, 1);
        g += __shfl_xor(g, 2);
        if ((tid & 3) == 0) atomicAdd(&ud_part[jj >> 2], g);
    }
    __syncthreads();
    if (tid < OC) UDp[blockIdx.x * OC + tid] = ud_part[tid];
}

// K2: all 3 routing iterations + squash. US column hoisted to registers
// (iteration-invariant). q=0 softmax skipped: b=0 -> c = 1/32 exactly, and
// (sum u)*2^-5 == sum(u*2^-5) bit-exactly (power-of-two scale; validated
// rounds 1-3). Barrier protocol: release fetch_add on bar (no threadfence
// drain), acquire polls; bar on its OWN 128B line so polls don't contend
// with the nacc RMWs. grid 10 x 1024 = one t per thread.
__global__ __launch_bounds__(1024) void k_route(const float* __restrict__ US,
                                                const float* __restrict__ UDp,
                                                float* __restrict__ nacc,
                                                int* __restrict__ bar,
                                                float* __restrict__ out) {
    const int tid = threadIdx.x;
    const int i   = tid & 31;          // in-capsule (tid<320 path)
    const int o   = tid >> 5;          // 0..9     (tid<320 path)
    __shared__ float cij[OC * IC];     // [o][i]
    __shared__ float wred[16];
    __shared__ float nsh;
    const int t  = blockIdx.x * 1024 + tid;   // b*160 + o*16 + e
    const int ot = (t >> 4) % OC;
    // hoist US column into registers: same values every iteration
    float usv[IC];
    {
        const float* usp = US + t;
        #pragma unroll
        for (int ii = 0; ii < IC; ++ii) usv[ii] = usp[(size_t)ii * BJ];
    }
    float udv = 0.f;
    if (tid < 320) {                   // ud[i][o] = sum over 16 bt tiles
        #pragma unroll
        for (int bt = 0; bt < 16; ++bt) udv += UDp[(bt * 32 + i) * OC + o];
    }
    float bij = 0.f;
    for (int q = 0; q < 3; ++q) {
        float cs = 0.f;
        float s  = 0.f;
        if (q == 0) {
            // b_ij = 0 -> c = 1/32 exactly; power-of-two scale is exact
            #pragma unroll
            for (int ii = 0; ii < IC; ++ii) s += usv[ii];
            s *= 0.03125f;
            if (tid < 320) {
                cs = udv;
                cs += __shfl_xor(cs, 16, 32);
                cs += __shfl_xor(cs,  8, 32);
                cs += __shfl_xor(cs,  4, 32);
                cs += __shfl_xor(cs,  2, 32);
                cs += __shfl_xor(cs,  1, 32);
                cs *= 0.03125f;
            }
        } else {
            if (tid < 320) {
                // softmax over i (32 aligned lanes) for this o
                float m = bij;
                m = fmaxf(m, __shfl_xor(m, 16, 32));
                m = fmaxf(m, __shfl_xor(m,  8, 32));
                m = fmaxf(m, __shfl_xor(m,  4, 32));
                m = fmaxf(m, __shfl_xor(m,  2, 32));
                m = fmaxf(m, __shfl_xor(m,  1, 32));
                float e  = __expf(bij - m);
                float se = e;
                se += __shfl_xor(se, 16, 32);
                se += __shfl_xor(se,  8, 32);
                se += __shfl_xor(se,  4, 32);
                se += __shfl_xor(se,  2, 32);
                se += __shfl_xor(se,  1, 32);
                float c = e / se;
                cij[o * IC + i] = c;
                cs = c * udv;          // Σ_i c·ud for this o (butterfly)
                cs += __shfl_xor(cs, 16, 32);
                cs += __shfl_xor(cs,  8, 32);
                cs += __shfl_xor(cs,  4, 32);
                cs += __shfl_xor(cs,  2, 32);
                cs += __shfl_xor(cs,  1, 32);
            }
            __syncthreads();           // cij visible
            const float* cp = cij + ot * IC;
            #pragma unroll
            for (int ii = 0; ii < IC; ++ii) s += cp[ii] * usv[ii];
        }
        float a = fabsf(s);
        #pragma unroll
        for (int off = 32; off; off >>= 1) a += __shfl_down(a, off);
        if ((tid & 63) == 0) wred[tid >> 6] = a;
        __syncthreads();
        if (tid == 0) {
            float blk = 0.f;
            #pragma unroll
            for (int w = 0; w < 16; ++w) blk += wred[w];
            atomicAdd(nacc + q, blk);
            // release: orders the nacc add before the arrival
            __hip_atomic_fetch_add(bar, 1, __ATOMIC_RELEASE,
                                   __HIP_MEMORY_SCOPE_AGENT);
            while (__hip_atomic_load(bar, __ATOMIC_ACQUIRE,
                                     __HIP_MEMORY_SCOPE_AGENT) < 10 * (q + 1))
                __builtin_amdgcn_s_sleep(1);
            nsh = __hip_atomic_load(nacc + q, __ATOMIC_RELAXED,
                                    __HIP_MEMORY_SCOPE_AGENT);
        }
        __syncthreads();
        const float n  = nsh;
        const float n2 = n * n;
        if (q < 2) {
            if (tid < 320) bij += udv * ((n2 / (1.f + n2)) * (cs / n));
        } else {
            out[t] = (n2 / (1.f + n2)) * (s / n);
        }
    }
}

extern "C" void kernel_launch(void* const* d_in, const int* in_sizes, int n_in,
                              void* d_out, int out_size, void* d_ws, size_t ws_size,
                              hipStream_t stream) {
    (void)in_sizes; (void)n_in; (void)out_size; (void)ws_size;
    const float* u  = (const float*)d_in[0];
    const float* Wt = (const float*)d_in[1];
    float* ws   = (float*)d_ws;
    float* US   = ws;               // 327680 floats
    float* UDp  = ws + 327680;      // 5120 floats
    float* nacc = ws + 332800;      // 3 floats (own 128B line)
    int*   bar  = (int*)(ws + 332832);  // own 128B line

    // 2 dispatches. k_usum zero-inits nacc/bar (ws poisoned each launch);
    // stream order guarantees readiness + US/UDp visibility for k_route.
    k_usum <<<dim3(512), dim3(320),  0, stream>>>(u, Wt, US, UDp, nacc, bar);
    k_route<<<dim3(10),  dim3(1024), 0, stream>>>(US, UDp, nacc, bar, (float*)d_out);
}